// Round 4
// baseline (108.330 us; speedup 1.0000x reference)
//
#include <hip/hip_runtime.h>
#include <hip/hip_bf16.h>
#include <math.h>

// Problem constants
#define TGT 560
#define B_ 2
#define K_ 1600
#define D_ 1024
#define C_ 256
#define N_ 32
#define P_ 40
#define KC_ 32      // k-chunks in kB
#define KCHUNK 50   // K_/KC_

// ws layout (float offsets)
#define OFF_IFN ((size_t)0)                      // B*K = 3200 inverse feat norms
#define OFF_IEN (OFF_IFN + (size_t)B_ * K_)      // C = 256 inverse emb norms
#define OFF_BOXW (OFF_IEN + (size_t)C_)          // B*N*80 (wy*invcnt | wx)
#define OFF_GP  ((size_t)16384)                  // B*KC*N*D = 2,097,152 floats (8 MB)

// ---- Kernel A: inverse row norms (feats+emb) + per-box separable bicubic weights ----
__global__ __launch_bounds__(256) void kA(const float* __restrict__ feats,
                                          const float* __restrict__ emb,
                                          const int* __restrict__ boxes,
                                          float* __restrict__ ws) {
    __shared__ float shm[80];
    const int r = blockIdx.x;
    const int t = threadIdx.x;
    if (r < B_ * K_ + C_) {
        // ---- row norm block ----
        const float* src;
        float* dst;
        if (r < B_ * K_) { src = feats + (size_t)r * D_; dst = ws + OFF_IFN + r; }
        else             { src = emb + (size_t)(r - B_ * K_) * D_; dst = ws + OFF_IEN + (r - B_ * K_); }
        float4 v = ((const float4*)src)[t];
        float s = v.x * v.x + v.y * v.y + v.z * v.z + v.w * v.w;
        #pragma unroll
        for (int off = 32; off > 0; off >>= 1) s += __shfl_down(s, off, 64);
        if ((t & 63) == 0) shm[t >> 6] = s;
        __syncthreads();
        if (t == 0) {
            float tot = shm[0] + shm[1] + shm[2] + shm[3];
            *dst = 1.0f / sqrtf(tot);   // eps fold: rel err ~1e-11, negligible
        }
    } else {
        // ---- box-weight block (one per bn) ----
        const int bn = r - (B_ * K_ + C_);
        if (t < 80) shm[t] = 0.f;
        __syncthreads();
        const int* bx = boxes + bn * 4;
        const int xmin = bx[0], ymin = bx[1], xmax = bx[2], ymax = bx[3];
        const float invcnt = 1.0f / ((float)(ymax - 1 - ymin) * (float)(xmax - 1 - xmin));
        const int axis = t >> 7;                       // 0 -> y, 1 -> x
        const int rr = t & 127;
        const int lo = (axis ? xmin : ymin);
        const int hi = (axis ? xmax : ymax) - 2;       // inclusive
        for (int h = lo + rr; h <= hi; h += 128) {
            float sf = ((float)h + 0.5f) * (1.0f / 14.0f) - 0.5f;
            int jf = (int)floorf(sf);
            float w[4];
            float norm = 0.f;
            #pragma unroll
            for (int dj = -1; dj <= 2; ++dj) {
                int j = jf + dj;
                float x = fabsf(sf - (float)j);
                float wv = ((1.5f * x - 2.5f) * x) * x + 1.f;            // |x|<1 (Keys a=-0.5)
                if (x >= 1.f) wv = ((-0.5f * x + 2.5f) * x - 4.f) * x + 2.f; // 1<=|x|<2
                if (x >= 2.f) wv = 0.f;
                if (j < 0 || j >= P_) wv = 0.f;        // edge: tap outside -> renorm below
                w[dj + 1] = wv;
                norm += wv;
            }
            float inv = 1.0f / norm;
            #pragma unroll
            for (int dj = 0; dj < 4; ++dj) {
                int j = jf - 1 + dj;
                if (w[dj] != 0.f) atomicAdd(&shm[axis * P_ + j], w[dj] * inv);
            }
        }
        __syncthreads();
        if (t < 80) {
            float val = shm[t];
            if (t < P_) val *= invcnt;                 // fold 1/count into wy
            ws[OFF_BOXW + (size_t)bn * 80 + t] = val;
        }
    }
}

// ---- Kernel B: gp[b][kc][n][d] = sum_{k in chunk} v[b,n,k] * feats[b,k,d] (block-unique stores) ----
__global__ __launch_bounds__(256) void kB(const float* __restrict__ feats,
                                          const float* __restrict__ ws,
                                          float* __restrict__ gp) {
    __shared__ float sw[N_ * 80];
    __shared__ float vlds[KCHUNK * N_];
    const int bid = blockIdx.x;          // 256 blocks: b(2) x kc(32) x dt(4)
    const int b = bid >> 7;
    const int rest = bid & 127;
    const int kc = rest >> 2;
    const int dt = rest & 3;
    const int t = threadIdx.x;
    const int k0 = kc * KCHUNK;

    for (int i = t; i < N_ * 80; i += 256)
        sw[i] = ws[OFF_BOXW + (size_t)b * N_ * 80 + i];
    __syncthreads();
    const float* ifn = ws + OFF_IFN + (size_t)b * K_;
    for (int i = t; i < KCHUNK * N_; i += 256) {
        int kk = i >> 5, n = i & 31;
        int k = k0 + kk;
        int pq = k / P_;
        int q = k - pq * P_;
        vlds[kk * N_ + n] = sw[n * 80 + pq] * sw[n * 80 + P_ + q] * ifn[k];
    }
    __syncthreads();

    float acc[N_];
    #pragma unroll
    for (int n = 0; n < N_; ++n) acc[n] = 0.f;

    const float* fp = feats + ((size_t)b * K_ + k0) * D_ + dt * 256 + t;
    #pragma unroll
    for (int gi = 0; gi < 5; ++gi) {
        float f[10];
        #pragma unroll
        for (int u = 0; u < 10; ++u) f[u] = fp[(size_t)(gi * 10 + u) * D_];  // 10 loads in flight
        #pragma unroll
        for (int u = 0; u < 10; ++u) {
            const float4* vp = (const float4*)&vlds[(gi * 10 + u) * N_];
            #pragma unroll
            for (int j = 0; j < 8; ++j) {            // broadcast b128 reads
                float4 v4 = vp[j];
                acc[4 * j + 0] = fmaf(v4.x, f[u], acc[4 * j + 0]);
                acc[4 * j + 1] = fmaf(v4.y, f[u], acc[4 * j + 1]);
                acc[4 * j + 2] = fmaf(v4.z, f[u], acc[4 * j + 2]);
                acc[4 * j + 3] = fmaf(v4.w, f[u], acc[4 * j + 3]);
            }
        }
    }
    float* o = gp + (((size_t)b * KC_ + kc) * N_) * D_ + dt * 256 + t;
    #pragma unroll
    for (int n = 0; n < N_; ++n) o[(size_t)n * D_] = acc[n];   // unique per (b,kc,n,d)
}

// ---- Kernel C: g[bn] = sum_kc gp; out[bn][c] = (1/|e_c|) * <g[bn], emb[c]> ----
// 64 blocks: bng(16, 4 bn each) x ct(4, 64 c each)
__global__ __launch_bounds__(256) void kC(const float* __restrict__ emb,
                                          const float* __restrict__ gp,
                                          const float* __restrict__ ien,
                                          float* __restrict__ out) {
    __shared__ float4 g4sh[4][D_ / 4];   // 16 KB
    __shared__ float part[4 * 256];      // 4 KB
    const int bid = blockIdx.x;
    const int bng = bid >> 2;
    const int ct = bid & 3;
    const int t = threadIdx.x;

    // Phase 1: reduce gp over kc for 4 bn rows
    const float4* gp4 = (const float4*)gp;
    #pragma unroll
    for (int bn = 0; bn < 4; ++bn) {
        int bnn = bng * 4 + bn;
        int b = bnn >> 5, n = bnn & 31;
        float4 a = {0.f, 0.f, 0.f, 0.f};
        #pragma unroll 4
        for (int kc = 0; kc < KC_; ++kc) {
            float4 x = gp4[(((size_t)b * KC_ + kc) * N_ + n) * (D_ / 4) + t];
            a.x += x.x; a.y += x.y; a.z += x.z; a.w += x.w;
        }
        g4sh[bn][t] = a;
    }
    __syncthreads();

    // Phase 2: dot with 64 emb rows
    const int cl = t & 63;
    const int dq = t >> 6;              // wave-uniform -> broadcast LDS reads
    const int c = ct * 64 + cl;
    const float4* e4 = (const float4*)(emb + (size_t)c * D_) + dq * 64;
    float p0 = 0.f, p1 = 0.f, p2 = 0.f, p3 = 0.f;
    #pragma unroll 4
    for (int i = 0; i < 64; ++i) {
        float4 e = e4[i];
        float4 g0 = g4sh[0][dq * 64 + i];
        float4 g1 = g4sh[1][dq * 64 + i];
        float4 g2 = g4sh[2][dq * 64 + i];
        float4 g3 = g4sh[3][dq * 64 + i];
        p0 += e.x * g0.x + e.y * g0.y + e.z * g0.z + e.w * g0.w;
        p1 += e.x * g1.x + e.y * g1.y + e.z * g1.z + e.w * g1.w;
        p2 += e.x * g2.x + e.y * g2.y + e.z * g2.z + e.w * g2.w;
        p3 += e.x * g3.x + e.y * g3.y + e.z * g3.z + e.w * g3.w;
    }
    part[0 * 256 + t] = p0;
    part[1 * 256 + t] = p1;
    part[2 * 256 + t] = p2;
    part[3 * 256 + t] = p3;
    __syncthreads();

    if (t < 64) {
        float sc = ien[ct * 64 + t];
        #pragma unroll
        for (int bn = 0; bn < 4; ++bn) {
            float val = part[bn * 256 + t] + part[bn * 256 + 64 + t] +
                        part[bn * 256 + 128 + t] + part[bn * 256 + 192 + t];
            out[(size_t)(bng * 4 + bn) * C_ + ct * 64 + t] = val * sc;
        }
    }
}

extern "C" void kernel_launch(void* const* d_in, const int* in_sizes, int n_in,
                              void* d_out, int out_size, void* d_ws, size_t ws_size,
                              hipStream_t stream) {
    const float* feats = (const float*)d_in[0];
    const float* emb   = (const float*)d_in[1];
    const int*   boxes = (const int*)d_in[2];
    float* out = (float*)d_out;
    float* ws  = (float*)d_ws;

    kA<<<B_ * K_ + C_ + B_ * N_, 256, 0, stream>>>(feats, emb, boxes, ws);
    kB<<<B_ * KC_ * 4, 256, 0, stream>>>(feats, ws, ws + OFF_GP);
    kC<<<B_ * N_ * 2, 256, 0, stream>>>(emb, ws + OFF_GP, ws + OFF_IEN, out);
}

// Round 5
// 90.917 us; speedup vs baseline: 1.1915x; 1.1915x over previous
//
#include <hip/hip_runtime.h>
#include <hip/hip_bf16.h>
#include <math.h>

// Problem constants
#define TGT 560
#define B_ 2
#define K_ 1600
#define D_ 1024
#define C_ 256
#define N_ 32
#define P_ 40
#define KC_ 32      // k-chunks in kB
#define KCHUNK 50   // K_/KC_

// ws layout (float offsets)
#define OFF_IFN ((size_t)0)                      // B*K = 3200 inverse feat norms
#define OFF_IEN (OFF_IFN + (size_t)B_ * K_)      // C = 256 inverse emb norms
#define OFF_BOXW (OFF_IEN + (size_t)C_)          // B*N*80 (wy*invcnt | wx)
#define OFF_G   ((size_t)16384)                  // B*N*D = 65536 floats (256 KB)

// ---- Kernel A: inverse row norms (feats+emb), per-box separable bicubic weights, zero g ----
__global__ __launch_bounds__(256) void kA(const float* __restrict__ feats,
                                          const float* __restrict__ emb,
                                          const int* __restrict__ boxes,
                                          float* __restrict__ ws) {
    __shared__ float shm[80];
    const int r = blockIdx.x;
    const int t = threadIdx.x;
    if (r < B_ * K_ + C_) {
        // ---- row norm block ----
        const float* src;
        float* dst;
        if (r < B_ * K_) { src = feats + (size_t)r * D_; dst = ws + OFF_IFN + r; }
        else             { src = emb + (size_t)(r - B_ * K_) * D_; dst = ws + OFF_IEN + (r - B_ * K_); }
        float4 v = ((const float4*)src)[t];
        float s = v.x * v.x + v.y * v.y + v.z * v.z + v.w * v.w;
        #pragma unroll
        for (int off = 32; off > 0; off >>= 1) s += __shfl_down(s, off, 64);
        if ((t & 63) == 0) shm[t >> 6] = s;
        __syncthreads();
        if (t == 0) {
            float tot = shm[0] + shm[1] + shm[2] + shm[3];
            *dst = 1.0f / sqrtf(tot);   // eps fold: rel err ~1e-11, negligible
        }
    } else {
        // ---- box-weight block (one per bn): also zero-init g[bn][:] for kB's atomics ----
        const int bn = r - (B_ * K_ + C_);
        ((float4*)(ws + OFF_G + (size_t)bn * D_))[t] = make_float4(0.f, 0.f, 0.f, 0.f);
        if (t < 80) shm[t] = 0.f;
        __syncthreads();
        const int* bx = boxes + bn * 4;
        const int xmin = bx[0], ymin = bx[1], xmax = bx[2], ymax = bx[3];
        const float invcnt = 1.0f / ((float)(ymax - 1 - ymin) * (float)(xmax - 1 - xmin));
        const int axis = t >> 7;                       // 0 -> y, 1 -> x
        const int rr = t & 127;
        const int lo = (axis ? xmin : ymin);
        const int hi = (axis ? xmax : ymax) - 2;       // inclusive
        for (int h = lo + rr; h <= hi; h += 128) {
            float sf = ((float)h + 0.5f) * (1.0f / 14.0f) - 0.5f;
            int jf = (int)floorf(sf);
            float w[4];
            float norm = 0.f;
            #pragma unroll
            for (int dj = -1; dj <= 2; ++dj) {
                int j = jf + dj;
                float x = fabsf(sf - (float)j);
                float wv = ((1.5f * x - 2.5f) * x) * x + 1.f;            // |x|<1 (Keys a=-0.5)
                if (x >= 1.f) wv = ((-0.5f * x + 2.5f) * x - 4.f) * x + 2.f; // 1<=|x|<2
                if (x >= 2.f) wv = 0.f;
                if (j < 0 || j >= P_) wv = 0.f;        // edge: tap outside -> renorm below
                w[dj + 1] = wv;
                norm += wv;
            }
            float inv = 1.0f / norm;
            #pragma unroll
            for (int dj = 0; dj < 4; ++dj) {
                int j = jf - 1 + dj;
                if (w[dj] != 0.f) atomicAdd(&shm[axis * P_ + j], w[dj] * inv);
            }
        }
        __syncthreads();
        if (t < 80) {
            float val = shm[t];
            if (t < P_) val *= invcnt;                 // fold 1/count into wy
            ws[OFF_BOXW + (size_t)bn * 80 + t] = val;
        }
    }
}

// ---- Kernel B: g[b][n][d] += sum_{k in chunk} v[b,n,k] * feats[b,k,d] (device atomics) ----
__global__ __launch_bounds__(256) void kB(const float* __restrict__ feats,
                                          const float* __restrict__ ws,
                                          float* __restrict__ g) {
    __shared__ float sw[N_ * 80];
    __shared__ float vlds[KCHUNK * N_];
    const int bid = blockIdx.x;          // 256 blocks: b(2) x kc(32) x dt(4)
    const int b = bid >> 7;
    const int rest = bid & 127;
    const int kc = rest >> 2;
    const int dt = rest & 3;
    const int t = threadIdx.x;
    const int k0 = kc * KCHUNK;

    for (int i = t; i < N_ * 80; i += 256)
        sw[i] = ws[OFF_BOXW + (size_t)b * N_ * 80 + i];
    __syncthreads();
    const float* ifn = ws + OFF_IFN + (size_t)b * K_;
    for (int i = t; i < KCHUNK * N_; i += 256) {
        int kk = i >> 5, n = i & 31;
        int k = k0 + kk;
        int pq = k / P_;
        int q = k - pq * P_;
        vlds[kk * N_ + n] = sw[n * 80 + pq] * sw[n * 80 + P_ + q] * ifn[k];
    }
    __syncthreads();

    float acc[N_];
    #pragma unroll
    for (int n = 0; n < N_; ++n) acc[n] = 0.f;

    const float* fp = feats + ((size_t)b * K_ + k0) * D_ + dt * 256 + t;
    #pragma unroll
    for (int gi = 0; gi < 5; ++gi) {
        float f[10];
        #pragma unroll
        for (int u = 0; u < 10; ++u) f[u] = fp[(size_t)(gi * 10 + u) * D_];  // 10 loads in flight
        #pragma unroll
        for (int u = 0; u < 10; ++u) {
            const float4* vp = (const float4*)&vlds[(gi * 10 + u) * N_];
            #pragma unroll
            for (int j = 0; j < 8; ++j) {            // broadcast b128 reads
                float4 v4 = vp[j];
                acc[4 * j + 0] = fmaf(v4.x, f[u], acc[4 * j + 0]);
                acc[4 * j + 1] = fmaf(v4.y, f[u], acc[4 * j + 1]);
                acc[4 * j + 2] = fmaf(v4.z, f[u], acc[4 * j + 2]);
                acc[4 * j + 3] = fmaf(v4.w, f[u], acc[4 * j + 3]);
            }
        }
    }
    float* o = g + (size_t)b * N_ * D_ + dt * 256 + t;
    #pragma unroll
    for (int n = 0; n < N_; ++n) atomicAdd(&o[(size_t)n * D_], acc[n]);
}

// ---- Kernel C: out[bn][c] = (1/|e_c|) * <g[bn,:], emb[c,:]> ----
// 256 blocks: bng(16, 4 bn rows) x ct(16, 16 emb rows). Each wave owns 4 distinct c rows.
__global__ __launch_bounds__(256) void kC(const float* __restrict__ emb,
                                          const float* __restrict__ g,
                                          const float* __restrict__ ien,
                                          float* __restrict__ out) {
    __shared__ float4 g4sh[4][D_ / 4];   // 16 KB: 4 box rows
    __shared__ float part[16][4];        // [c_local][bn]
    const int bid = blockIdx.x;
    const int bng = bid >> 4;
    const int ct  = bid & 15;
    const int t = threadIdx.x;
    const int lane = t & 63;
    const int wv = t >> 6;

    #pragma unroll
    for (int bn = 0; bn < 4; ++bn)
        g4sh[bn][t] = ((const float4*)(g + (size_t)(bng * 4 + bn) * D_))[t];
    __syncthreads();

    float p[4][4];                       // [cc][bn]
    #pragma unroll
    for (int cc = 0; cc < 4; ++cc)
        #pragma unroll
        for (int bn = 0; bn < 4; ++bn) p[cc][bn] = 0.f;

    #pragma unroll
    for (int i = 0; i < 4; ++i) {
        float4 gv[4];
        #pragma unroll
        for (int bn = 0; bn < 4; ++bn) gv[bn] = g4sh[bn][lane + 64 * i];
        #pragma unroll
        for (int cc = 0; cc < 4; ++cc) {
            const int c = ct * 16 + wv * 4 + cc;
            float4 e = ((const float4*)(emb + (size_t)c * D_))[lane + 64 * i];
            #pragma unroll
            for (int bn = 0; bn < 4; ++bn)
                p[cc][bn] += e.x * gv[bn].x + e.y * gv[bn].y + e.z * gv[bn].z + e.w * gv[bn].w;
        }
    }
    #pragma unroll
    for (int cc = 0; cc < 4; ++cc) {
        #pragma unroll
        for (int bn = 0; bn < 4; ++bn) {
            float v = p[cc][bn];
            #pragma unroll
            for (int off = 32; off > 0; off >>= 1) v += __shfl_down(v, off, 64);
            if (lane == 0) part[wv * 4 + cc][bn] = v;
        }
    }
    __syncthreads();
    if (t < 64) {
        const int c = t >> 2, bn = t & 3;
        out[(size_t)(bng * 4 + bn) * C_ + ct * 16 + c] = part[c][bn] * ien[ct * 16 + c];
    }
}

extern "C" void kernel_launch(void* const* d_in, const int* in_sizes, int n_in,
                              void* d_out, int out_size, void* d_ws, size_t ws_size,
                              hipStream_t stream) {
    const float* feats = (const float*)d_in[0];
    const float* emb   = (const float*)d_in[1];
    const int*   boxes = (const int*)d_in[2];
    float* out = (float*)d_out;
    float* ws  = (float*)d_ws;

    kA<<<B_ * K_ + C_ + B_ * N_, 256, 0, stream>>>(feats, emb, boxes, ws);
    kB<<<B_ * KC_ * 4, 256, 0, stream>>>(feats, ws, ws + OFF_G);
    kC<<<256, 256, 0, stream>>>(emb, ws + OFF_G, ws + OFF_IEN, out);
}